// Round 7
// baseline (5467.785 us; speedup 1.0000x reference)
//
#include <hip/hip_runtime.h>
#include <stdint.h>

typedef unsigned short u16;
typedef unsigned int u32;
typedef unsigned long long u64;
typedef __attribute__((ext_vector_type(8))) short short8;
typedef __attribute__((ext_vector_type(4))) float f32x4;
typedef __attribute__((ext_vector_type(4))) unsigned int u32x4;

#define B_ 32
#define S_ 512
#define H_ 1024
#define NBLK 64   // recurrence workgroups (<=256 CUs -> co-resident, dataflow-safe)

// ---- workspace layout (bytes) ----
// ht: tagged h double buffer, u32 {bf16 | tag<<16}: 2*32*1024*4 = 256 KB.
static const size_t OFF_HT   = 0;                         // tagged h [2][32][1024] u32
static const size_t OFF_DFLG = 262144;                    // dtype flag
static const size_t OFF_BIAS = 262400;                    // fp32[4096]
static const size_t OFF_UT   = OFF_BIAS + 16384;          // U^T bf16 [4096][1024]
static const size_t OFF_VP   = OFF_UT + 8388608;          // V fragment-permuted bf16
static const size_t OFF_XU   = OFF_VP + 8388608;          // xu bf16 [512][32][4096]
static const size_t WS_NEED  = OFF_XU + (size_t)S_ * B_ * 4 * H_ * 2;

__device__ inline float bf2f(u16 u) {
    union { unsigned i; float f; } v; v.i = ((unsigned)u) << 16; return v.f;
}
__device__ inline u16 f2bf(float f) {
    union { float f; unsigned i; } v; v.f = f;
    unsigned r = v.i + 0x7fffu + ((v.i >> 16) & 1u);   // RNE
    return (u16)(r >> 16);
}
__device__ inline float sigm(float x) { return 1.0f / (1.0f + __expf(-x)); }
__device__ inline float tanh_(float x) {
    x = fminf(fmaxf(x, -30.0f), 30.0f);
    float e = __expf(-2.0f * x);
    return (1.0f - e) / (1.0f + e);
}
// NaN-proof clamp: fmaxf/fminf drop a NaN operand -> result always finite.
__device__ inline float zclamp(float x) { return fminf(fmaxf(x, -60.0f), 60.0f); }

// dual-dtype element read -> bf16 bits
__device__ inline u16 rd_bf(const void* p, size_t idx, int isbf) {
    return isbf ? ((const u16*)p)[idx] : f2bf(((const float*)p)[idx]);
}
__device__ inline float rd_f(const void* p, size_t idx, int isbf) {
    return isbf ? bf2f(((const u16*)p)[idx]) : ((const float*)p)[idx];
}

// system-scope 16B load (bypass stale L1/L2, served by coherent LLC).
// No implicit waitcnt -> caller batches then waits once.
__device__ inline void llc_load_u32x4(const u32* p, u32x4& d) {
    asm volatile("global_load_dwordx4 %0, %1, off sc0 sc1"
                 : "=&v"(d) : "v"(p));
}

// ---------------- dtype probe ----------------
__global__ void prep_probe(const void* x, int* flag) {
    if (blockIdx.x == 0 && threadIdx.x == 0) {
        const u16* p = (const u16*)x;
        int bfish = 0;
        for (int i = 0; i < 512; i += 2) {
            int e = (p[i] >> 7) & 0xFF;
            if (e >= 118 && e <= 131) ++bfish;
        }
        flag[0] = (bfish >= 128) ? 1 : 0;   // 1 = bf16 buffers, 0 = fp32 buffers
    }
}

// ---------------- prep kernels ----------------

__global__ void prep_misc(const void* b0, const void* b1, const void* b2, const void* b3,
                          float* __restrict__ bias, const void* h0,
                          u32* __restrict__ ht, const int* __restrict__ flag) {
    const int isbf = flag[0];
    int i = blockIdx.x * 256 + threadIdx.x;
    if (i < 4096) {
        int g = i >> 10, n = i & 1023;
        const void* bp = (g == 0) ? b0 : (g == 1) ? b1 : (g == 2) ? b2 : b3;
        bias[i] = rd_f(bp, n, isbf);
    }
    int j = i - 4096;
    if (j >= 0 && j < B_ * H_) ht[j] = (u32)rd_bf(h0, j, isbf);   // tag 0
}

// Ut[(g*1024+n)*1024 + k] = U_g[k*1024 + n]
__global__ void prep_ut(const void* u0, const void* u1, const void* u2, const void* u3,
                        u16* __restrict__ Ut, const int* __restrict__ flag) {
    const int isbf = flag[0];
    int idx = blockIdx.x * 256 + threadIdx.x;          // [4][128][1024]
    int g  = idx >> 17;
    int k8 = (idx >> 10) & 127;
    int n  = idx & 1023;
    const void* Ug = (g == 0) ? u0 : (g == 1) ? u1 : (g == 2) ? u2 : u3;
    int k0 = k8 * 8;
    union { u16 a[8]; short8 v; } t;
#pragma unroll
    for (int j = 0; j < 8; ++j) t.a[j] = rd_bf(Ug, (size_t)(k0 + j) * 1024 + n, isbf);
    *(short8*)(Ut + ((size_t)(g * 1024 + n) * 1024 + k0)) = t.v;
}

// Vp[((g*64+nb)*32+ks)*64+lane][8] = V_g[k][n], n=nb*16+(lane&15), k=ks*32+(lane>>4)*8+j
__global__ void prep_vp(const void* v0, const void* v1, const void* v2, const void* v3,
                        u16* __restrict__ Vp, const int* __restrict__ flag) {
    const int isbf = flag[0];
    int idx = blockIdx.x * 256 + threadIdx.x;          // [4][64][32][64]
    int lane = idx & 63;
    int ks = (idx >> 6) & 31;
    int nb = (idx >> 11) & 63;
    int g  = idx >> 17;
    const void* Vg = (g == 0) ? v0 : (g == 1) ? v1 : (g == 2) ? v2 : v3;
    int n  = nb * 16 + (lane & 15);
    int kb = ks * 32 + (lane >> 4) * 8;
    union { u16 a[8]; short8 v; } t;
#pragma unroll
    for (int j = 0; j < 8; ++j) t.a[j] = rd_bf(Vg, (size_t)(kb + j) * 1024 + n, isbf);
    *(short8*)(Vp + (size_t)idx * 8) = t.v;
}

// ---------------- phase 1: xu = x @ U + b  (bf16 out, [s][b][4096]) ----------------

__global__ __launch_bounds__(256) void gemm_xu(
    const void* __restrict__ xv, const u16* __restrict__ Ut,
    const float* __restrict__ bias, u16* __restrict__ xu,
    const int* __restrict__ flag) {
    const int isbf = flag[0];
    const int bx = blockIdx.x;
    const int m0 = (bx & 127) * 128;
    const int n0 = (bx >> 7) * 128;
    const int tid = threadIdx.x;
    const int w = tid >> 6, lane = tid & 63;
    const int lm = lane & 15, q = lane >> 4;
    const int r4 = lane >> 2, c4 = lane & 3;

    __shared__ __attribute__((aligned(16))) u16 As[128 * 32];
    __shared__ __attribute__((aligned(16))) u16 Bs[128 * 32];

    const int mb = (w >> 1) * 64, nbL = (w & 1) * 64;
    f32x4 acc[4][4] = {};

    for (int k0 = 0; k0 < 1024; k0 += 32) {
        __syncthreads();
#pragma unroll
        for (int i2 = 0; i2 < 2; ++i2) {
            const int i = w * 2 + i2;
            const size_t aoff = (size_t)(m0 + i * 16 + r4) * 1024 + k0 + c4 * 8;
            if (isbf) {
                const u16* ga = (const u16*)xv + aoff;
                __builtin_amdgcn_global_load_lds((const __attribute__((address_space(1))) void*)ga,
                                                 (__attribute__((address_space(3))) void*)(As + i * 512),
                                                 16, 0, 0);
            } else {
                const float* ga = (const float*)xv + aoff;
                f32x4 f0 = *(const f32x4*)ga;
                f32x4 f1 = *(const f32x4*)(ga + 4);
                union { u16 a[8]; short8 v; } t;
#pragma unroll
                for (int j = 0; j < 4; ++j) { t.a[j] = f2bf(f0[j]); t.a[4 + j] = f2bf(f1[j]); }
                *(short8*)(As + i * 512 + lane * 8) = t.v;
            }
            const u16* gb = Ut + (size_t)(n0 + i * 16 + r4) * 1024 + k0 + c4 * 8;
            __builtin_amdgcn_global_load_lds((const __attribute__((address_space(1))) void*)gb,
                                             (__attribute__((address_space(3))) void*)(Bs + i * 512),
                                             16, 0, 0);
        }
        __syncthreads();

        short8 af[4], bf[4];
#pragma unroll
        for (int mt = 0; mt < 4; ++mt)
            af[mt] = *(const short8*)(As + (mb + mt * 16 + lm) * 32 + q * 8);
#pragma unroll
        for (int nt = 0; nt < 4; ++nt)
            bf[nt] = *(const short8*)(Bs + (nbL + nt * 16 + lm) * 32 + q * 8);
#pragma unroll
        for (int mt = 0; mt < 4; ++mt)
#pragma unroll
            for (int nt = 0; nt < 4; ++nt)
                acc[mt][nt] = __builtin_amdgcn_mfma_f32_16x16x32_bf16(af[mt], bf[nt], acc[mt][nt], 0, 0, 0);
    }

#pragma unroll
    for (int mt = 0; mt < 4; ++mt) {
#pragma unroll
        for (int nt = 0; nt < 4; ++nt) {
            const int ng = n0 + nbL + nt * 16 + lm;
            const float bv = bias[ng];
#pragma unroll
            for (int r = 0; r < 4; ++r) {
                const int m = m0 + mb + mt * 16 + q * 4 + r;   // m = b*512 + s
                const int s = m & 511, b = m >> 9;
                xu[(size_t)(s * 32 + b) * 4096 + ng] = f2bf(acc[mt][nt][r] + bv);
            }
        }
    }
}

// ---------------- phase 2: persistent recurrence ----------------
// Round-7: TAGGED-WORD h exchange (exact seqlock) — no flags, no drains.
// Model fix: step 11.6k cy = ring of ~4 serial uncached-LLC round trips
// (RT ~2k cy on this multi-die part) + compute. R4->R6 fixes each removed
// ~1k => attack the RT COUNT. Each h value is stored as ONE u32
// {bf16 | step_tag<<16}: 4B stores are single-copy atomic, so tag and
// datum are inseparable -> writer needs NO drain and NO flag; reader
// batch-loads tagged words and verifies tag==t on every word (exact, not
// probabilistic; stale reads show tag t-2 or 0xFFFF init, never torn).
// Any stale tag -> re-issue h loads (retry IS the throttle).
// Back-pressure: a writer reaches step t+1 only after verifying all tags
// t+1... which every WG stores only after finishing its step-t READS ->
// a buffer is never overwritten while some WG still reads it (skew<=1,
// parity double-buffer safe). Serial chain per step collapses to
// ~1 load+verify RT (+occasional retry) + compute.
// h/out-stores are fire-and-forget (drained in parallel by the NEXT
// verify-wait); xu(t+1) prefetched during step t.

__global__ __launch_bounds__(256, 1) void lstm_rec(
    const u16* __restrict__ xu, const u16* __restrict__ Vp,
    const void* __restrict__ c0, u32* ht, void* outv,
    const int* __restrict__ flag) {
    const int isbf = flag[0];
    const int nb = blockIdx.x;
    const int tid = threadIdx.x;
    const int w = tid >> 6;
    const int lane = tid & 63;
    const int lm = lane & 15;
    const int q = lane >> 4;

    // V gates 1..3: [g-1][ks][lane*8]  (1KB blocks, matches global_load_lds pattern)
    __shared__ __attribute__((aligned(16))) u16 Vl[3 * 32 * 512];     // 96 KiB
    __shared__ float part[4][4][2][16][18];   // [wave][gate][mt][row][col] pad 18

    const int em = tid >> 4;                   // batch row 0..15
    const int en = tid & 15;
    const int ncol = nb * 16 + en;             // col within gate

    float c_a = rd_f(c0, (size_t)em * H_ + ncol, isbf);
    float c_b = rd_f(c0, (size_t)(em + 16) * H_ + ncol, isbf);

    float* outf = (float*)outv;
    u16*   outh = (u16*)outv;

    // ---- gate-0 V fragments in registers (32 VGPR, constant across steps) ----
    short8 bpre0[8];
#pragma unroll
    for (int kk = 0; kk < 8; ++kk) {
        const int ks = w * 8 + kk;
        bpre0[kk] = *(const short8*)(Vp + ((((size_t)0 * 64 + nb) * 32 + ks) * 64 + lane) * 8);
    }

    // ---- gates 1..3 V -> LDS once (96 blocks of 1KB; wave w takes b = w,w+4,..) ----
    for (int b = w; b < 96; b += 4) {
        const int gq = b >> 5;                 // 0..2 -> gate gq+1
        const int ks = b & 31;
        const u16* src = Vp + ((((size_t)(gq + 1) * 64 + nb) * 32 + ks) * 64 + lane) * 8;
        __builtin_amdgcn_global_load_lds((const __attribute__((address_space(1))) void*)src,
                                         (__attribute__((address_space(3))) void*)(Vl + b * 512),
                                         16, 0, 0);
    }

    // ---- prefetch xu for t=0 ----
    u16 xva[4], xvb[4];
#pragma unroll
    for (int g = 0; g < 4; ++g) {
        xva[g] = xu[em * 4096 + g * 1024 + ncol];
        xvb[g] = xu[(em + 16) * 4096 + g * 1024 + ncol];
    }
    __syncthreads();   // Vl + xu(0) ready

    float hA = 0.f, hB = 0.f;
    u16 hAb = 0, hBb = 0;

#pragma unroll 1
    for (int t = 0; t < S_; ++t) {
        const u32* hb32 = ht + (size_t)(t & 1) * (B_ * H_);
        const u32 exphi = (u32)t << 16;

        // ---- 1) tagged h load + verify (retry until every word has tag t) ----
        u32x4 ra[8][2], rb[8][2];
#pragma unroll 1
        for (;;) {
#pragma unroll
            for (int kk = 0; kk < 8; ++kk) {
                const int ks = w * 8 + kk;
                const u32* p0 = hb32 + lm * H_ + ks * 32 + q * 8;
                const u32* p1 = hb32 + (lm + 16) * H_ + ks * 32 + q * 8;
                llc_load_u32x4(p0,     ra[kk][0]);
                llc_load_u32x4(p0 + 4, ra[kk][1]);
                llc_load_u32x4(p1,     rb[kk][0]);
                llc_load_u32x4(p1 + 4, rb[kk][1]);
            }
            asm volatile("s_waitcnt vmcnt(0)" ::: "memory");
            __builtin_amdgcn_sched_barrier(0);
            u32 bad = 0;
#pragma unroll
            for (int kk = 0; kk < 8; ++kk)
#pragma unroll
                for (int i = 0; i < 2; ++i)
#pragma unroll
                    for (int j = 0; j < 4; ++j) {
                        bad |= (ra[kk][i][j] ^ exphi) & 0xFFFF0000u;
                        bad |= (rb[kk][i][j] ^ exphi) & 0xFFFF0000u;
                    }
            if (__all(bad == 0)) break;
        }

        // ---- 2) pack tagged words -> bf16 A-fragments ----
        short8 ha[8], hbv[8];
#pragma unroll
        for (int kk = 0; kk < 8; ++kk) {
            union { u32 u[4]; short8 s; } pa, pb;
#pragma unroll
            for (int i = 0; i < 2; ++i) {
                pa.u[i * 2 + 0] = (ra[kk][i][0] & 0xFFFFu) | (ra[kk][i][1] << 16);
                pa.u[i * 2 + 1] = (ra[kk][i][2] & 0xFFFFu) | (ra[kk][i][3] << 16);
                pb.u[i * 2 + 0] = (rb[kk][i][0] & 0xFFFFu) | (rb[kk][i][1] << 16);
                pb.u[i * 2 + 1] = (rb[kk][i][2] & 0xFFFFu) | (rb[kk][i][3] << 16);
            }
            ha[kk]  = pa.s;
            hbv[kk] = pb.s;
        }

        // ---- 3) MFMA phase: gate0 from regs, gates1..3 from LDS ----
        f32x4 acc[4][2] = {};
#pragma unroll
        for (int kk = 0; kk < 8; ++kk) {
            const int ks = w * 8 + kk;
            const short8 b1 = *(const short8*)(Vl + (0 * 32 + ks) * 512 + lane * 8);
            const short8 b2 = *(const short8*)(Vl + (1 * 32 + ks) * 512 + lane * 8);
            const short8 b3 = *(const short8*)(Vl + (2 * 32 + ks) * 512 + lane * 8);
            acc[0][0] = __builtin_amdgcn_mfma_f32_16x16x32_bf16(ha[kk],  bpre0[kk], acc[0][0], 0, 0, 0);
            acc[0][1] = __builtin_amdgcn_mfma_f32_16x16x32_bf16(hbv[kk], bpre0[kk], acc[0][1], 0, 0, 0);
            acc[1][0] = __builtin_amdgcn_mfma_f32_16x16x32_bf16(ha[kk],  b1, acc[1][0], 0, 0, 0);
            acc[1][1] = __builtin_amdgcn_mfma_f32_16x16x32_bf16(hbv[kk], b1, acc[1][1], 0, 0, 0);
            acc[2][0] = __builtin_amdgcn_mfma_f32_16x16x32_bf16(ha[kk],  b2, acc[2][0], 0, 0, 0);
            acc[2][1] = __builtin_amdgcn_mfma_f32_16x16x32_bf16(hbv[kk], b2, acc[2][1], 0, 0, 0);
            acc[3][0] = __builtin_amdgcn_mfma_f32_16x16x32_bf16(ha[kk],  b3, acc[3][0], 0, 0, 0);
            acc[3][1] = __builtin_amdgcn_mfma_f32_16x16x32_bf16(hbv[kk], b3, acc[3][1], 0, 0, 0);
        }

        // ---- 4) partials -> LDS, cross-wave reduce, elementwise ----
#pragma unroll
        for (int g = 0; g < 4; ++g)
#pragma unroll
            for (int mt = 0; mt < 2; ++mt)
#pragma unroll
                for (int r = 0; r < 4; ++r)
                    part[w][g][mt][q * 4 + r][lm] = acc[g][mt][r];
        __syncthreads();

        float z_a[4], z_b[4];
#pragma unroll
        for (int g = 0; g < 4; ++g) {
            z_a[g] = zclamp(bf2f(xva[g]) + part[0][g][0][em][en] + part[1][g][0][em][en]
                                         + part[2][g][0][em][en] + part[3][g][0][em][en]);
            z_b[g] = zclamp(bf2f(xvb[g]) + part[0][g][1][em][en] + part[1][g][1][em][en]
                                         + part[2][g][1][em][en] + part[3][g][1][em][en]);
        }

        float ia = sigm(z_a[0]), fa = sigm(z_a[1]), ga = tanh_(z_a[2]), oa = sigm(z_a[3]);
        c_a = fa * c_a + ia * ga;
        hA = oa * tanh_(c_a);
        float ib = sigm(z_b[0]), fb = sigm(z_b[1]), gb = tanh_(z_b[2]), ob = sigm(z_b[3]);
        c_b = fb * c_b + ib * gb;
        hB = ob * tanh_(c_b);

        hAb = f2bf(hA); hBb = f2bf(hB);

        // ---- 5) tagged h-stores (fire-and-forget) + out-stores + xu(t+1) ----
        {
            u32* hn = ht + (size_t)((t + 1) & 1) * (B_ * H_);
            const u32 tagn = (u32)(t + 1) << 16;
            __hip_atomic_store(&hn[em * H_ + ncol],        (u32)hAb | tagn,
                               __ATOMIC_RELAXED, __HIP_MEMORY_SCOPE_AGENT);
            __hip_atomic_store(&hn[(em + 16) * H_ + ncol], (u32)hBb | tagn,
                               __ATOMIC_RELAXED, __HIP_MEMORY_SCOPE_AGENT);
        }

        const size_t oA = ((size_t)em * S_ + t) * H_ + ncol;
        const size_t oB = ((size_t)(em + 16) * S_ + t) * H_ + ncol;
        if (isbf) { outh[oA] = hAb; outh[oB] = hBb; }
        else      { outf[oA] = hA;  outf[oB] = hB;  }

        {
            const u16* xt = xu + (size_t)((t + 1) & (S_ - 1)) * (B_ * 4 * H_);
#pragma unroll
            for (int g = 0; g < 4; ++g) {
                xva[g] = xt[em * 4096 + g * 1024 + ncol];
                xvb[g] = xt[(em + 16) * 4096 + g * 1024 + ncol];
            }
        }

        __syncthreads();   // part[] reuse guard (reads above vs next-step writes)
    }

    // ---- epilogue: final h/c ----
    {
        const size_t HS = (size_t)B_ * S_ * H_;
        const size_t hA_i = HS + (size_t)em * H_ + ncol;
        const size_t hB_i = HS + (size_t)(em + 16) * H_ + ncol;
        const size_t cA_i = HS + (size_t)B_ * H_ + (size_t)em * H_ + ncol;
        const size_t cB_i = HS + (size_t)B_ * H_ + (size_t)(em + 16) * H_ + ncol;
        if (isbf) {
            outh[hA_i] = hAb; outh[hB_i] = hBb;
            outh[cA_i] = f2bf(c_a); outh[cB_i] = f2bf(c_b);
        } else {
            outf[hA_i] = hA; outf[hB_i] = hB;
            outf[cA_i] = c_a; outf[cB_i] = c_b;
        }
    }
}

// ---------------- host ----------------

extern "C" void kernel_launch(void* const* d_in, const int* in_sizes, int n_in,
                              void* d_out, int out_size, void* d_ws, size_t ws_size,
                              hipStream_t stream) {
    (void)in_sizes; (void)n_in; (void)out_size;
    if (ws_size < WS_NEED) return;   // diagnostic: out stays 0 -> absmax ~0.89 signature
    const void* x  = d_in[0];
    const void* h0 = d_in[1];
    const void* c0 = d_in[2];
    const void* U0 = d_in[3],  *V0 = d_in[4],  *bb0 = d_in[5];
    const void* U1 = d_in[6],  *V1 = d_in[7],  *bb1 = d_in[8];
    const void* U2 = d_in[9],  *V2 = d_in[10], *bb2 = d_in[11];
    const void* U3 = d_in[12], *V3 = d_in[13], *bb3 = d_in[14];

    char* ws = (char*)d_ws;
    u32*   ht    = (u32*)(ws + OFF_HT);      // tagged h double buffer
    int*   dflg  = (int*)(ws + OFF_DFLG);    // dtype flag
    float* bias  = (float*)(ws + OFF_BIAS);
    u16*   Ut    = (u16*)(ws + OFF_UT);
    u16*   Vp    = (u16*)(ws + OFF_VP);
    u16*   xu    = (u16*)(ws + OFF_XU);

    // tags init: 0xFFFF (never a valid step tag); prep_misc overwrites par0 with tag 0
    hipMemsetAsync(ht, 0xFF, 262144, stream);
    prep_probe<<<dim3(1), dim3(64), 0, stream>>>(x, dflg);
    prep_misc<<<dim3(144), dim3(256), 0, stream>>>(bb0, bb1, bb2, bb3, bias, h0, ht, dflg);
    prep_ut<<<dim3(2048), dim3(256), 0, stream>>>(U0, U1, U2, U3, Ut, dflg);
    prep_vp<<<dim3(2048), dim3(256), 0, stream>>>(V0, V1, V2, V3, Vp, dflg);
    gemm_xu<<<dim3(4096), dim3(256), 0, stream>>>(x, Ut, bias, xu, dflg);
    lstm_rec<<<dim3(NBLK), dim3(256), 0, stream>>>(xu, Vp, c0, ht, (void*)d_out, dflg);
}

// Round 8
// 3489.075 us; speedup vs baseline: 1.5671x; 1.5671x over previous
//
#include <hip/hip_runtime.h>
#include <stdint.h>

typedef unsigned short u16;
typedef unsigned int u32;
typedef unsigned long long u64;
typedef __attribute__((ext_vector_type(8))) short short8;
typedef __attribute__((ext_vector_type(4))) float f32x4;

#define B_ 32
#define S_ 512
#define H_ 1024
#define NBLK 64   // recurrence workgroups (<=256 CUs -> co-resident, spin barrier safe)

// ---- workspace layout (bytes) ----
// flags: 64 ints at 64B stride (spread over 32 x 128B lines) -> 8KB region.
static const size_t OFF_FLG  = 0;                         // flags[64] @ stride 16 ints
static const size_t OFF_HBF  = 8192;                      // h double buffer: 2*32*1024*2
static const size_t OFF_DFLG = OFF_HBF + 131072;          // dtype flag (256B pad)
static const size_t OFF_BIAS = OFF_HBF + 131072 + 256;    // fp32[4096]
static const size_t OFF_UT   = OFF_BIAS + 16384;          // U^T bf16 [4096][1024]
static const size_t OFF_VP   = OFF_UT + 8388608;          // V fragment-permuted bf16
static const size_t OFF_XU   = OFF_VP + 8388608;          // xu bf16 [512][32][4096]
static const size_t WS_NEED  = OFF_XU + (size_t)S_ * B_ * 4 * H_ * 2;

__device__ inline float bf2f(u16 u) {
    union { unsigned i; float f; } v; v.i = ((unsigned)u) << 16; return v.f;
}
__device__ inline u16 f2bf(float f) {
    union { float f; unsigned i; } v; v.f = f;
    unsigned r = v.i + 0x7fffu + ((v.i >> 16) & 1u);   // RNE
    return (u16)(r >> 16);
}
__device__ inline float sigm(float x) { return 1.0f / (1.0f + __expf(-x)); }
__device__ inline float tanh_(float x) {
    x = fminf(fmaxf(x, -30.0f), 30.0f);
    float e = __expf(-2.0f * x);
    return (1.0f - e) / (1.0f + e);
}
// NaN-proof clamp: fmaxf/fminf drop a NaN operand -> result always finite.
__device__ inline float zclamp(float x) { return fminf(fmaxf(x, -60.0f), 60.0f); }

// dual-dtype element read -> bf16 bits
__device__ inline u16 rd_bf(const void* p, size_t idx, int isbf) {
    return isbf ? ((const u16*)p)[idx] : f2bf(((const float*)p)[idx]);
}
__device__ inline float rd_f(const void* p, size_t idx, int isbf) {
    return isbf ? bf2f(((const u16*)p)[idx]) : ((const float*)p)[idx];
}

// ---------------- dtype probe ----------------
__global__ void prep_probe(const void* x, int* flag) {
    if (blockIdx.x == 0 && threadIdx.x == 0) {
        const u16* p = (const u16*)x;
        int bfish = 0;
        for (int i = 0; i < 512; i += 2) {
            int e = (p[i] >> 7) & 0xFF;
            if (e >= 118 && e <= 131) ++bfish;
        }
        flag[0] = (bfish >= 128) ? 1 : 0;   // 1 = bf16 buffers, 0 = fp32 buffers
    }
}

// ---------------- prep kernels ----------------

__global__ void prep_misc(const void* b0, const void* b1, const void* b2, const void* b3,
                          float* __restrict__ bias, const void* h0,
                          u16* __restrict__ hbf, const int* __restrict__ flag) {
    const int isbf = flag[0];
    int i = blockIdx.x * 256 + threadIdx.x;
    if (i < 4096) {
        int g = i >> 10, n = i & 1023;
        const void* bp = (g == 0) ? b0 : (g == 1) ? b1 : (g == 2) ? b2 : b3;
        bias[i] = rd_f(bp, n, isbf);
    }
    int j = i - 4096;
    if (j >= 0 && j < B_ * H_) hbf[j] = rd_bf(h0, j, isbf);
}

// Ut[(g*1024+n)*1024 + k] = U_g[k*1024 + n]
__global__ void prep_ut(const void* u0, const void* u1, const void* u2, const void* u3,
                        u16* __restrict__ Ut, const int* __restrict__ flag) {
    const int isbf = flag[0];
    int idx = blockIdx.x * 256 + threadIdx.x;          // [4][128][1024]
    int g  = idx >> 17;
    int k8 = (idx >> 10) & 127;
    int n  = idx & 1023;
    const void* Ug = (g == 0) ? u0 : (g == 1) ? u1 : (g == 2) ? u2 : u3;
    int k0 = k8 * 8;
    union { u16 a[8]; short8 v; } t;
#pragma unroll
    for (int j = 0; j < 8; ++j) t.a[j] = rd_bf(Ug, (size_t)(k0 + j) * 1024 + n, isbf);
    *(short8*)(Ut + ((size_t)(g * 1024 + n) * 1024 + k0)) = t.v;
}

// Vp[((g*64+nb)*32+ks)*64+lane][8] = V_g[k][n], n=nb*16+(lane&15), k=ks*32+(lane>>4)*8+j
__global__ void prep_vp(const void* v0, const void* v1, const void* v2, const void* v3,
                        u16* __restrict__ Vp, const int* __restrict__ flag) {
    const int isbf = flag[0];
    int idx = blockIdx.x * 256 + threadIdx.x;          // [4][64][32][64]
    int lane = idx & 63;
    int ks = (idx >> 6) & 31;
    int nb = (idx >> 11) & 63;
    int g  = idx >> 17;
    const void* Vg = (g == 0) ? v0 : (g == 1) ? v1 : (g == 2) ? v2 : v3;
    int n  = nb * 16 + (lane & 15);
    int kb = ks * 32 + (lane >> 4) * 8;
    union { u16 a[8]; short8 v; } t;
#pragma unroll
    for (int j = 0; j < 8; ++j) t.a[j] = rd_bf(Vg, (size_t)(kb + j) * 1024 + n, isbf);
    *(short8*)(Vp + (size_t)idx * 8) = t.v;
}

// ---------------- phase 1: xu = x @ U + b  (bf16 out, [s][b][4096]) ----------------

__global__ __launch_bounds__(256) void gemm_xu(
    const void* __restrict__ xv, const u16* __restrict__ Ut,
    const float* __restrict__ bias, u16* __restrict__ xu,
    const int* __restrict__ flag) {
    const int isbf = flag[0];
    const int bx = blockIdx.x;
    const int m0 = (bx & 127) * 128;
    const int n0 = (bx >> 7) * 128;
    const int tid = threadIdx.x;
    const int w = tid >> 6, lane = tid & 63;
    const int lm = lane & 15, q = lane >> 4;
    const int r4 = lane >> 2, c4 = lane & 3;

    __shared__ __attribute__((aligned(16))) u16 As[128 * 32];
    __shared__ __attribute__((aligned(16))) u16 Bs[128 * 32];

    const int mb = (w >> 1) * 64, nbL = (w & 1) * 64;
    f32x4 acc[4][4] = {};

    for (int k0 = 0; k0 < 1024; k0 += 32) {
        __syncthreads();
#pragma unroll
        for (int i2 = 0; i2 < 2; ++i2) {
            const int i = w * 2 + i2;
            const size_t aoff = (size_t)(m0 + i * 16 + r4) * 1024 + k0 + c4 * 8;
            if (isbf) {
                const u16* ga = (const u16*)xv + aoff;
                __builtin_amdgcn_global_load_lds((const __attribute__((address_space(1))) void*)ga,
                                                 (__attribute__((address_space(3))) void*)(As + i * 512),
                                                 16, 0, 0);
            } else {
                const float* ga = (const float*)xv + aoff;
                f32x4 f0 = *(const f32x4*)ga;
                f32x4 f1 = *(const f32x4*)(ga + 4);
                union { u16 a[8]; short8 v; } t;
#pragma unroll
                for (int j = 0; j < 4; ++j) { t.a[j] = f2bf(f0[j]); t.a[4 + j] = f2bf(f1[j]); }
                *(short8*)(As + i * 512 + lane * 8) = t.v;
            }
            const u16* gb = Ut + (size_t)(n0 + i * 16 + r4) * 1024 + k0 + c4 * 8;
            __builtin_amdgcn_global_load_lds((const __attribute__((address_space(1))) void*)gb,
                                             (__attribute__((address_space(3))) void*)(Bs + i * 512),
                                             16, 0, 0);
        }
        __syncthreads();

        short8 af[4], bf[4];
#pragma unroll
        for (int mt = 0; mt < 4; ++mt)
            af[mt] = *(const short8*)(As + (mb + mt * 16 + lm) * 32 + q * 8);
#pragma unroll
        for (int nt = 0; nt < 4; ++nt)
            bf[nt] = *(const short8*)(Bs + (nbL + nt * 16 + lm) * 32 + q * 8);
#pragma unroll
        for (int mt = 0; mt < 4; ++mt)
#pragma unroll
            for (int nt = 0; nt < 4; ++nt)
                acc[mt][nt] = __builtin_amdgcn_mfma_f32_16x16x32_bf16(af[mt], bf[nt], acc[mt][nt], 0, 0, 0);
    }

#pragma unroll
    for (int mt = 0; mt < 4; ++mt) {
#pragma unroll
        for (int nt = 0; nt < 4; ++nt) {
            const int ng = n0 + nbL + nt * 16 + lm;
            const float bv = bias[ng];
#pragma unroll
            for (int r = 0; r < 4; ++r) {
                const int m = m0 + mb + mt * 16 + q * 4 + r;   // m = b*512 + s
                const int s = m & 511, b = m >> 9;
                xu[(size_t)(s * 32 + b) * 4096 + ng] = f2bf(acc[mt][nt][r] + bv);
            }
        }
    }
}

// ---------------- phase 2: persistent recurrence ----------------
// Round-8: R6 skeleton (flag-array barrier, one grid sync per step) +
// per-XCD L2 CACHING of the h broadcast:
//  * R7 taught: h exchange is BANDWIDTH too — 64 WGs x 64KB = 4MB/step
//    through the LLC with uncached sc1 loads (and tagging doubled it).
//  * Fix: relaxed sc1 poll (no L2 traffic) -> ONE acquire fence at agent
//    scope AFTER poll success (s_waitcnt + buffer_inv: L1/L2 invalidated
//    once per step, NOT per poll iteration) -> PLAIN CACHED h loads.
//    Each XCD fetches the 64KB h buffer from LLC once; its ~8 WGs hit L2.
//    Cross-die traffic 4MB -> ~512KB/step.
//  * Dirty-L2 hazard: buffer_inv (ours or a co-XCD WG's) drops dirty L2
//    lines -> every must-survive store is sc1 WRITE-THROUGH atomic:
//    h-stores (already), out-stores, epilogue. Nothing valuable dirty.
//  * Out-stores moved AFTER flag release: pre-flag drain covers only the
//    two 2B h-stores; HBM out-acks retire inside the next detect phase.
// Ordering: writer h-stores(sc1) -> vmcnt(0) -> __syncthreads -> tid0
// flag store. Reader: poll flags >= t -> acquire fence (inv) -> cached
// h loads (fresh from LLC by construction).

__global__ __launch_bounds__(256, 1) void lstm_rec(
    const u16* __restrict__ xu, const u16* __restrict__ Vp,
    const void* __restrict__ c0, u16* h_bf, void* outv, int* flags,
    const int* __restrict__ flag) {
    const int isbf = flag[0];
    const int nb = blockIdx.x;
    const int tid = threadIdx.x;
    const int w = tid >> 6;
    const int lane = tid & 63;
    const int lm = lane & 15;
    const int q = lane >> 4;

    // V gates 1..3: [g-1][ks][lane*8]  (1KB blocks, matches global_load_lds pattern)
    __shared__ __attribute__((aligned(16))) u16 Vl[3 * 32 * 512];     // 96 KiB
    __shared__ float part[4][4][2][16][18];   // [wave][gate][mt][row][col] pad 18

    const int em = tid >> 4;                   // batch row 0..15
    const int en = tid & 15;
    const int ncol = nb * 16 + en;             // col within gate

    float c_a = rd_f(c0, (size_t)em * H_ + ncol, isbf);
    float c_b = rd_f(c0, (size_t)(em + 16) * H_ + ncol, isbf);

    float* outf = (float*)outv;
    u16*   outh = (u16*)outv;

    // ---- gate-0 V fragments in registers (32 VGPR, constant across steps) ----
    short8 bpre0[8];
#pragma unroll
    for (int kk = 0; kk < 8; ++kk) {
        const int ks = w * 8 + kk;
        bpre0[kk] = *(const short8*)(Vp + ((((size_t)0 * 64 + nb) * 32 + ks) * 64 + lane) * 8);
    }

    // ---- gates 1..3 V -> LDS once (96 blocks of 1KB; wave w takes b = w,w+4,..) ----
    for (int b = w; b < 96; b += 4) {
        const int gq = b >> 5;                 // 0..2 -> gate gq+1
        const int ks = b & 31;
        const u16* src = Vp + ((((size_t)(gq + 1) * 64 + nb) * 32 + ks) * 64 + lane) * 8;
        __builtin_amdgcn_global_load_lds((const __attribute__((address_space(1))) void*)src,
                                         (__attribute__((address_space(3))) void*)(Vl + b * 512),
                                         16, 0, 0);
    }
    __syncthreads();   // drains vmcnt: Vl ready

    float hA = 0.f, hB = 0.f;
    u16 hAb = 0, hBb = 0;
    float pA = 0.f, pB = 0.f;       // previous-step h for deferred out-store
    u16 pAb = 0, pBb = 0;

#pragma unroll 1
    for (int t = 0; t < S_; ++t) {
        const int par = t & 1;

        // ---- 0) flag-array wait: relaxed sc1 poll (no L2 pollution) ----
        if (t) {
            while (true) {
                int v = __hip_atomic_load(&flags[lane * 16], __ATOMIC_RELAXED, __HIP_MEMORY_SCOPE_AGENT);
                if (__all(v >= t)) break;
            }
        }
        // ONE acquire fence per step: drains vmcnt (incl. deferred out-acks)
        // and invalidates L1/L2 -> cached h loads below are provably fresh.
        __builtin_amdgcn_fence(__ATOMIC_ACQUIRE, "agent");

        // ---- 1) batched CACHED loads for step t: 16 x 16B h + 8 xu, ONE wait ----
        const u16* hb = h_bf + par * (B_ * H_);
        short8 ha[8], hbv[8];
#pragma unroll
        for (int kk = 0; kk < 8; ++kk) {
            const int ks = w * 8 + kk;
            ha[kk]  = *(const short8*)(hb + lm * H_ + ks * 32 + q * 8);
            hbv[kk] = *(const short8*)(hb + (lm + 16) * H_ + ks * 32 + q * 8);
        }
        u16 xva[4], xvb[4];
        {
            const u16* xt = xu + (size_t)t * (B_ * 4 * H_);
#pragma unroll
            for (int g = 0; g < 4; ++g) {
                xva[g] = xt[em * 4096 + g * 1024 + ncol];
                xvb[g] = xt[(em + 16) * 4096 + g * 1024 + ncol];
            }
        }
        asm volatile("s_waitcnt vmcnt(0)" ::: "memory");
        __builtin_amdgcn_sched_barrier(0);

        // ---- 2) MFMA phase: gate0 from regs, gates1..3 from LDS ----
        f32x4 acc[4][2] = {};
#pragma unroll
        for (int kk = 0; kk < 8; ++kk) {
            const int ks = w * 8 + kk;
            const short8 b1 = *(const short8*)(Vl + (0 * 32 + ks) * 512 + lane * 8);
            const short8 b2 = *(const short8*)(Vl + (1 * 32 + ks) * 512 + lane * 8);
            const short8 b3 = *(const short8*)(Vl + (2 * 32 + ks) * 512 + lane * 8);
            acc[0][0] = __builtin_amdgcn_mfma_f32_16x16x32_bf16(ha[kk],  bpre0[kk], acc[0][0], 0, 0, 0);
            acc[0][1] = __builtin_amdgcn_mfma_f32_16x16x32_bf16(hbv[kk], bpre0[kk], acc[0][1], 0, 0, 0);
            acc[1][0] = __builtin_amdgcn_mfma_f32_16x16x32_bf16(ha[kk],  b1, acc[1][0], 0, 0, 0);
            acc[1][1] = __builtin_amdgcn_mfma_f32_16x16x32_bf16(hbv[kk], b1, acc[1][1], 0, 0, 0);
            acc[2][0] = __builtin_amdgcn_mfma_f32_16x16x32_bf16(ha[kk],  b2, acc[2][0], 0, 0, 0);
            acc[2][1] = __builtin_amdgcn_mfma_f32_16x16x32_bf16(hbv[kk], b2, acc[2][1], 0, 0, 0);
            acc[3][0] = __builtin_amdgcn_mfma_f32_16x16x32_bf16(ha[kk],  b3, acc[3][0], 0, 0, 0);
            acc[3][1] = __builtin_amdgcn_mfma_f32_16x16x32_bf16(hbv[kk], b3, acc[3][1], 0, 0, 0);
        }

        // ---- 3) partials -> LDS, cross-wave reduce, elementwise ----
#pragma unroll
        for (int g = 0; g < 4; ++g)
#pragma unroll
            for (int mt = 0; mt < 2; ++mt)
#pragma unroll
                for (int r = 0; r < 4; ++r)
                    part[w][g][mt][q * 4 + r][lm] = acc[g][mt][r];
        __syncthreads();

        float z_a[4], z_b[4];
#pragma unroll
        for (int g = 0; g < 4; ++g) {
            z_a[g] = zclamp(bf2f(xva[g]) + part[0][g][0][em][en] + part[1][g][0][em][en]
                                         + part[2][g][0][em][en] + part[3][g][0][em][en]);
            z_b[g] = zclamp(bf2f(xvb[g]) + part[0][g][1][em][en] + part[1][g][1][em][en]
                                         + part[2][g][1][em][en] + part[3][g][1][em][en]);
        }

        float ia = sigm(z_a[0]), fa = sigm(z_a[1]), ga = tanh_(z_a[2]), oa = sigm(z_a[3]);
        c_a = fa * c_a + ia * ga;
        hA = oa * tanh_(c_a);
        float ib = sigm(z_b[0]), fb = sigm(z_b[1]), gb = tanh_(z_b[2]), ob = sigm(z_b[3]);
        c_b = fb * c_b + ib * gb;
        hB = ob * tanh_(c_b);

        hAb = f2bf(hA); hBb = f2bf(hB);

        // ---- 4) h-stores (sc1 write-through) -> drain -> rendezvous -> flag ----
        u16* hn = h_bf + (par ^ 1) * (B_ * H_);
        __hip_atomic_store(&hn[em * H_ + ncol],        hAb, __ATOMIC_RELAXED, __HIP_MEMORY_SCOPE_AGENT);
        __hip_atomic_store(&hn[(em + 16) * H_ + ncol], hBb, __ATOMIC_RELAXED, __HIP_MEMORY_SCOPE_AGENT);
        asm volatile("s_waitcnt vmcnt(0)" ::: "memory");
        __syncthreads();   // all 4 waves' h-stores acked before flag release
        if (tid == 0)
            __hip_atomic_store(&flags[nb * 16], t + 1, __ATOMIC_RELAXED, __HIP_MEMORY_SCOPE_AGENT);

        // ---- 5) out-stores for step t: POST-flag, sc1 write-through (survive inv) ----
        {
            const size_t oA = ((size_t)em * S_ + t) * H_ + ncol;
            const size_t oB = ((size_t)(em + 16) * S_ + t) * H_ + ncol;
            if (isbf) {
                __hip_atomic_store(&outh[oA], hAb, __ATOMIC_RELAXED, __HIP_MEMORY_SCOPE_AGENT);
                __hip_atomic_store(&outh[oB], hBb, __ATOMIC_RELAXED, __HIP_MEMORY_SCOPE_AGENT);
            } else {
                __hip_atomic_store(&outf[oA], hA, __ATOMIC_RELAXED, __HIP_MEMORY_SCOPE_AGENT);
                __hip_atomic_store(&outf[oB], hB, __ATOMIC_RELAXED, __HIP_MEMORY_SCOPE_AGENT);
            }
        }
        pA = hA; pB = hB; pAb = hAb; pBb = hBb;
        (void)pA; (void)pB; (void)pAb; (void)pBb;
    }

    // ---- epilogue: final h/c (sc1 write-through: survive co-XCD invs) ----
    {
        const size_t HS = (size_t)B_ * S_ * H_;
        const size_t hA_i = HS + (size_t)em * H_ + ncol;
        const size_t hB_i = HS + (size_t)(em + 16) * H_ + ncol;
        const size_t cA_i = HS + (size_t)B_ * H_ + (size_t)em * H_ + ncol;
        const size_t cB_i = HS + (size_t)B_ * H_ + (size_t)(em + 16) * H_ + ncol;
        if (isbf) {
            __hip_atomic_store(&outh[hA_i], hAb, __ATOMIC_RELAXED, __HIP_MEMORY_SCOPE_AGENT);
            __hip_atomic_store(&outh[hB_i], hBb, __ATOMIC_RELAXED, __HIP_MEMORY_SCOPE_AGENT);
            __hip_atomic_store(&outh[cA_i], f2bf(c_a), __ATOMIC_RELAXED, __HIP_MEMORY_SCOPE_AGENT);
            __hip_atomic_store(&outh[cB_i], f2bf(c_b), __ATOMIC_RELAXED, __HIP_MEMORY_SCOPE_AGENT);
        } else {
            __hip_atomic_store(&outf[hA_i], hA, __ATOMIC_RELAXED, __HIP_MEMORY_SCOPE_AGENT);
            __hip_atomic_store(&outf[hB_i], hB, __ATOMIC_RELAXED, __HIP_MEMORY_SCOPE_AGENT);
            __hip_atomic_store(&outf[cA_i], c_a, __ATOMIC_RELAXED, __HIP_MEMORY_SCOPE_AGENT);
            __hip_atomic_store(&outf[cB_i], c_b, __ATOMIC_RELAXED, __HIP_MEMORY_SCOPE_AGENT);
        }
    }
}

// ---------------- host ----------------

extern "C" void kernel_launch(void* const* d_in, const int* in_sizes, int n_in,
                              void* d_out, int out_size, void* d_ws, size_t ws_size,
                              hipStream_t stream) {
    (void)in_sizes; (void)n_in; (void)out_size;
    if (ws_size < WS_NEED) return;   // diagnostic: out stays 0 -> absmax ~0.89 signature
    const void* x  = d_in[0];
    const void* h0 = d_in[1];
    const void* c0 = d_in[2];
    const void* U0 = d_in[3],  *V0 = d_in[4],  *bb0 = d_in[5];
    const void* U1 = d_in[6],  *V1 = d_in[7],  *bb1 = d_in[8];
    const void* U2 = d_in[9],  *V2 = d_in[10], *bb2 = d_in[11];
    const void* U3 = d_in[12], *V3 = d_in[13], *bb3 = d_in[14];

    char* ws = (char*)d_ws;
    int*   flags = (int*)(ws + OFF_FLG);     // 64 flags @ 64B stride
    int*   dflg  = (int*)(ws + OFF_DFLG);    // dtype flag
    u16*   hbf   = (u16*)(ws + OFF_HBF);
    float* bias  = (float*)(ws + OFF_BIAS);
    u16*   Ut    = (u16*)(ws + OFF_UT);
    u16*   Vp    = (u16*)(ws + OFF_VP);
    u16*   xu    = (u16*)(ws + OFF_XU);

    hipMemsetAsync(flags, 0, 8192, stream);
    prep_probe<<<dim3(1), dim3(64), 0, stream>>>(x, dflg);
    prep_misc<<<dim3(144), dim3(256), 0, stream>>>(bb0, bb1, bb2, bb3, bias, h0, hbf, dflg);
    prep_ut<<<dim3(2048), dim3(256), 0, stream>>>(U0, U1, U2, U3, Ut, dflg);
    prep_vp<<<dim3(2048), dim3(256), 0, stream>>>(V0, V1, V2, V3, Vp, dflg);
    gemm_xu<<<dim3(4096), dim3(256), 0, stream>>>(x, Ut, bias, xu, dflg);
    lstm_rec<<<dim3(NBLK), dim3(256), 0, stream>>>(xu, Vp, c0, hbf, (void*)d_out, flags, dflg);
}

// Round 10
// 2917.960 us; speedup vs baseline: 1.8738x; 1.1957x over previous
//
#include <hip/hip_runtime.h>
#include <stdint.h>

typedef unsigned short u16;
typedef unsigned int u32;
typedef unsigned long long u64;
typedef __attribute__((ext_vector_type(8))) short short8;
typedef __attribute__((ext_vector_type(4))) float f32x4;
typedef __attribute__((ext_vector_type(4))) unsigned int u32x4;

#define B_ 32
#define S_ 512
#define H_ 1024
#define NBLK 64   // recurrence workgroups (<=256 CUs -> co-resident, spin barrier safe)

// ---- workspace layout (bytes) ----
// flags: 64 WGs x 64B; WG nb's 4 per-wave flags = ints [nb*16 .. nb*16+3].
static const size_t OFF_FLG  = 0;                         // flags region, 4KB
static const size_t OFF_HBF  = 16384;                     // h double buffer: 2*32*1024*2
static const size_t OFF_DFLG = OFF_HBF + 131072;          // dtype flag (256B pad)
static const size_t OFF_BIAS = OFF_HBF + 131072 + 256;    // fp32[4096]
static const size_t OFF_UT   = OFF_BIAS + 16384;          // U^T bf16 [4096][1024]
static const size_t OFF_VP   = OFF_UT + 8388608;          // V fragment-permuted bf16
static const size_t OFF_XU   = OFF_VP + 8388608;          // xu bf16 [512][32][4096]
static const size_t WS_NEED  = OFF_XU + (size_t)S_ * B_ * 4 * H_ * 2;

__device__ inline float bf2f(u16 u) {
    union { unsigned i; float f; } v; v.i = ((unsigned)u) << 16; return v.f;
}
__device__ inline u16 f2bf(float f) {
    union { float f; unsigned i; } v; v.f = f;
    unsigned r = v.i + 0x7fffu + ((v.i >> 16) & 1u);   // RNE
    return (u16)(r >> 16);
}
__device__ inline float sigm(float x) { return 1.0f / (1.0f + __expf(-x)); }
__device__ inline float tanh_(float x) {
    x = fminf(fmaxf(x, -30.0f), 30.0f);
    float e = __expf(-2.0f * x);
    return (1.0f - e) / (1.0f + e);
}
// NaN-proof clamp: fmaxf/fminf drop a NaN operand -> result always finite.
__device__ inline float zclamp(float x) { return fminf(fmaxf(x, -60.0f), 60.0f); }

// dual-dtype element read -> bf16 bits
__device__ inline u16 rd_bf(const void* p, size_t idx, int isbf) {
    return isbf ? ((const u16*)p)[idx] : f2bf(((const float*)p)[idx]);
}
__device__ inline float rd_f(const void* p, size_t idx, int isbf) {
    return isbf ? bf2f(((const u16*)p)[idx]) : ((const float*)p)[idx];
}

// system-scope 16B load: bypass (possibly stale) per-CU L1 / per-XCD L2,
// served by the coherent memory-side Infinity Cache. Issues WITHOUT an
// implicit waitcnt -> caller batches N loads then waits ONCE.
__device__ inline short8 llc_load16(const u16* p) {
    u32x4 r;
    asm volatile("global_load_dwordx4 %0, %1, off sc0 sc1"
                 : "=&v"(r) : "v"(p));
    union { u32x4 u; short8 s; } cv; cv.u = r; return cv.s;
}

// ---------------- dtype probe ----------------
__global__ void prep_probe(const void* x, int* flag) {
    if (blockIdx.x == 0 && threadIdx.x == 0) {
        const u16* p = (const u16*)x;
        int bfish = 0;
        for (int i = 0; i < 512; i += 2) {
            int e = (p[i] >> 7) & 0xFF;
            if (e >= 118 && e <= 131) ++bfish;
        }
        flag[0] = (bfish >= 128) ? 1 : 0;   // 1 = bf16 buffers, 0 = fp32 buffers
    }
}

// ---------------- prep kernels ----------------

__global__ void prep_misc(const void* b0, const void* b1, const void* b2, const void* b3,
                          float* __restrict__ bias, const void* h0,
                          u16* __restrict__ hbf, const int* __restrict__ flag) {
    const int isbf = flag[0];
    int i = blockIdx.x * 256 + threadIdx.x;
    if (i < 4096) {
        int g = i >> 10, n = i & 1023;
        const void* bp = (g == 0) ? b0 : (g == 1) ? b1 : (g == 2) ? b2 : b3;
        bias[i] = rd_f(bp, n, isbf);
    }
    int j = i - 4096;
    if (j >= 0 && j < B_ * H_) hbf[j] = rd_bf(h0, j, isbf);
}

// Ut[(g*1024+n)*1024 + k] = U_g[k*1024 + n]
__global__ void prep_ut(const void* u0, const void* u1, const void* u2, const void* u3,
                        u16* __restrict__ Ut, const int* __restrict__ flag) {
    const int isbf = flag[0];
    int idx = blockIdx.x * 256 + threadIdx.x;          // [4][128][1024]
    int g  = idx >> 17;
    int k8 = (idx >> 10) & 127;
    int n  = idx & 1023;
    const void* Ug = (g == 0) ? u0 : (g == 1) ? u1 : (g == 2) ? u2 : u3;
    int k0 = k8 * 8;
    union { u16 a[8]; short8 v; } t;
#pragma unroll
    for (int j = 0; j < 8; ++j) t.a[j] = rd_bf(Ug, (size_t)(k0 + j) * 1024 + n, isbf);
    *(short8*)(Ut + ((size_t)(g * 1024 + n) * 1024 + k0)) = t.v;
}

// Vp[((g*64+nb)*32+ks)*64+lane][8] = V_g[k][n], n=nb*16+(lane&15), k=ks*32+(lane>>4)*8+j
__global__ void prep_vp(const void* v0, const void* v1, const void* v2, const void* v3,
                        u16* __restrict__ Vp, const int* __restrict__ flag) {
    const int isbf = flag[0];
    int idx = blockIdx.x * 256 + threadIdx.x;          // [4][64][32][64]
    int lane = idx & 63;
    int ks = (idx >> 6) & 31;
    int nb = (idx >> 11) & 63;
    int g  = idx >> 17;
    const void* Vg = (g == 0) ? v0 : (g == 1) ? v1 : (g == 2) ? v2 : v3;
    int n  = nb * 16 + (lane & 15);
    int kb = ks * 32 + (lane >> 4) * 8;
    union { u16 a[8]; short8 v; } t;
#pragma unroll
    for (int j = 0; j < 8; ++j) t.a[j] = rd_bf(Vg, (size_t)(kb + j) * 1024 + n, isbf);
    *(short8*)(Vp + (size_t)idx * 8) = t.v;
}

// ---------------- phase 1: xu = x @ U + b  (bf16 out, [s][b][4096]) ----------------

__global__ __launch_bounds__(256) void gemm_xu(
    const void* __restrict__ xv, const u16* __restrict__ Ut,
    const float* __restrict__ bias, u16* __restrict__ xu,
    const int* __restrict__ flag) {
    const int isbf = flag[0];
    const int bx = blockIdx.x;
    const int m0 = (bx & 127) * 128;
    const int n0 = (bx >> 7) * 128;
    const int tid = threadIdx.x;
    const int w = tid >> 6, lane = tid & 63;
    const int lm = lane & 15, q = lane >> 4;
    const int r4 = lane >> 2, c4 = lane & 3;

    __shared__ __attribute__((aligned(16))) u16 As[128 * 32];
    __shared__ __attribute__((aligned(16))) u16 Bs[128 * 32];

    const int mb = (w >> 1) * 64, nbL = (w & 1) * 64;
    f32x4 acc[4][4] = {};

    for (int k0 = 0; k0 < 1024; k0 += 32) {
        __syncthreads();
#pragma unroll
        for (int i2 = 0; i2 < 2; ++i2) {
            const int i = w * 2 + i2;
            const size_t aoff = (size_t)(m0 + i * 16 + r4) * 1024 + k0 + c4 * 8;
            if (isbf) {
                const u16* ga = (const u16*)xv + aoff;
                __builtin_amdgcn_global_load_lds((const __attribute__((address_space(1))) void*)ga,
                                                 (__attribute__((address_space(3))) void*)(As + i * 512),
                                                 16, 0, 0);
            } else {
                const float* ga = (const float*)xv + aoff;
                f32x4 f0 = *(const f32x4*)ga;
                f32x4 f1 = *(const f32x4*)(ga + 4);
                union { u16 a[8]; short8 v; } t;
#pragma unroll
                for (int j = 0; j < 4; ++j) { t.a[j] = f2bf(f0[j]); t.a[4 + j] = f2bf(f1[j]); }
                *(short8*)(As + i * 512 + lane * 8) = t.v;
            }
            const u16* gb = Ut + (size_t)(n0 + i * 16 + r4) * 1024 + k0 + c4 * 8;
            __builtin_amdgcn_global_load_lds((const __attribute__((address_space(1))) void*)gb,
                                             (__attribute__((address_space(3))) void*)(Bs + i * 512),
                                             16, 0, 0);
        }
        __syncthreads();

        short8 af[4], bf[4];
#pragma unroll
        for (int mt = 0; mt < 4; ++mt)
            af[mt] = *(const short8*)(As + (mb + mt * 16 + lm) * 32 + q * 8);
#pragma unroll
        for (int nt = 0; nt < 4; ++nt)
            bf[nt] = *(const short8*)(Bs + (nbL + nt * 16 + lm) * 32 + q * 8);
#pragma unroll
        for (int mt = 0; mt < 4; ++mt)
#pragma unroll
            for (int nt = 0; nt < 4; ++nt)
                acc[mt][nt] = __builtin_amdgcn_mfma_f32_16x16x32_bf16(af[mt], bf[nt], acc[mt][nt], 0, 0, 0);
    }

#pragma unroll
    for (int mt = 0; mt < 4; ++mt) {
#pragma unroll
        for (int nt = 0; nt < 4; ++nt) {
            const int ng = n0 + nbL + nt * 16 + lm;
            const float bv = bias[ng];
#pragma unroll
            for (int r = 0; r < 4; ++r) {
                const int m = m0 + mb + mt * 16 + q * 4 + r;   // m = b*512 + s
                const int s = m & 511, b = m >> 9;
                xu[(size_t)(s * 32 + b) * 4096 + ng] = f2bf(acc[mt][nt][r] + bv);
            }
        }
    }
}

// ---------------- phase 2: persistent recurrence ----------------
// Round-10 (= R9's intent, race-fixed): sc1 h exchange + PER-WAVE flag
// release + ALL-TO-ALL poll.
//  * R9 audit found: polling only each wave's PRODUCER set (16 WGs) loses
//    the buffer-free guarantee (consumers of my columns = one wave of ALL
//    64 WGs). Fix: WG nb's 4 wave-flags packed in one 16B group at
//    flags[nb*16..nb*16+3] (64B stride between WGs); reader lane l
//    gathers WG l's 4 flags in ONE dwordx4 and checks all 4 >= t.
//    All 256 wave-flags covered -> R6's skew proof restored at wave
//    granularity (flag >= t <=> wave finished step t-1 reads AND stores).
//  * Release stays per-wave: each wave drains ITS OWN h-stores
//    (s_waitcnt is per-wave) and stores its own int. NO __syncthreads on
//    the release path (R6 had drain -> syncthreads -> tid0 store).
//  * xu(t+1) prefetched at end of step t (retires during detect; in-order
//    vmcnt -> drained before the poll load is observed -> h-wait is pure).
//  * out-stores issued AFTER flag release; their acks retire inside the
//    next detect window (poll's own vmcnt wait covers them, overlapped).
//  * part[] hazards: two mid-loop __syncthreads (sync -> write -> sync ->
//    read), both OFF the release path.

__global__ __launch_bounds__(256, 1) void lstm_rec(
    const u16* __restrict__ xu, const u16* __restrict__ Vp,
    const void* __restrict__ c0, u16* h_bf, void* outv, int* flags,
    const int* __restrict__ flag) {
    const int isbf = flag[0];
    const int nb = blockIdx.x;
    const int tid = threadIdx.x;
    const int w = tid >> 6;
    const int lane = tid & 63;
    const int lm = lane & 15;
    const int q = lane >> 4;

    // V gates 1..3: [g-1][ks][lane*8]  (1KB blocks, matches global_load_lds pattern)
    __shared__ __attribute__((aligned(16))) u16 Vl[3 * 32 * 512];     // 96 KiB
    __shared__ float part[4][4][2][16][18];   // [wave][gate][mt][row][col] pad 18

    const int em = tid >> 4;                   // batch row 0..15
    const int en = tid & 15;
    const int ncol = nb * 16 + en;             // col within gate

    float c_a = rd_f(c0, (size_t)em * H_ + ncol, isbf);
    float c_b = rd_f(c0, (size_t)(em + 16) * H_ + ncol, isbf);

    float* outf = (float*)outv;
    u16*   outh = (u16*)outv;

    // ---- gate-0 V fragments in registers (32 VGPR, constant across steps) ----
    short8 bpre0[8];
#pragma unroll
    for (int kk = 0; kk < 8; ++kk) {
        const int ks = w * 8 + kk;
        bpre0[kk] = *(const short8*)(Vp + ((((size_t)0 * 64 + nb) * 32 + ks) * 64 + lane) * 8);
    }

    // ---- gates 1..3 V -> LDS once (96 blocks of 1KB; wave w takes b = w,w+4,..) ----
    for (int b = w; b < 96; b += 4) {
        const int gq = b >> 5;                 // 0..2 -> gate gq+1
        const int ks = b & 31;
        const u16* src = Vp + ((((size_t)(gq + 1) * 64 + nb) * 32 + ks) * 64 + lane) * 8;
        __builtin_amdgcn_global_load_lds((const __attribute__((address_space(1))) void*)src,
                                         (__attribute__((address_space(3))) void*)(Vl + b * 512),
                                         16, 0, 0);
    }

    // ---- prefetch xu for t=0 ----
    u16 xva[4], xvb[4];
#pragma unroll
    for (int g = 0; g < 4; ++g) {
        xva[g] = xu[em * 4096 + g * 1024 + ncol];
        xvb[g] = xu[(em + 16) * 4096 + g * 1024 + ncol];
    }
    __syncthreads();   // drains vmcnt: Vl + xu(0) ready

    float hA = 0.f, hB = 0.f;
    u16 hAb = 0, hBb = 0;

#pragma unroll 1
    for (int t = 0; t < S_; ++t) {
        const int par = t & 1;

        // ---- 0) all-to-all wait: lane l gathers WG l's 4 wave-flags (one load) ----
        if (t) {
            const int* fp = flags + lane * 16;
#pragma unroll 1
            for (;;) {
                u32x4 f;
                asm volatile("global_load_dwordx4 %0, %1, off sc0 sc1\n\t"
                             "s_waitcnt vmcnt(0)"
                             : "=&v"(f) : "v"(fp) : "memory");
                const bool ok = ((int)f[0] >= t) && ((int)f[1] >= t) &&
                                ((int)f[2] >= t) && ((int)f[3] >= t);
                if (__all(ok)) break;
            }
        }

        // ---- 1) batched h loads (sc1): 16 x 16B, ONE wait (xu already in regs) ----
        const u16* hb = h_bf + par * (B_ * H_);
        short8 ha[8], hbv[8];
#pragma unroll
        for (int kk = 0; kk < 8; ++kk) {
            const int ks = w * 8 + kk;
            ha[kk]  = llc_load16(hb + lm * H_ + ks * 32 + q * 8);
            hbv[kk] = llc_load16(hb + (lm + 16) * H_ + ks * 32 + q * 8);
        }
        asm volatile("s_waitcnt vmcnt(0)" ::: "memory");
        __builtin_amdgcn_sched_barrier(0);

        // ---- 2) MFMA phase: gate0 from regs, gates1..3 from LDS ----
        f32x4 acc[4][2] = {};
#pragma unroll
        for (int kk = 0; kk < 8; ++kk) {
            const int ks = w * 8 + kk;
            const short8 b1 = *(const short8*)(Vl + (0 * 32 + ks) * 512 + lane * 8);
            const short8 b2 = *(const short8*)(Vl + (1 * 32 + ks) * 512 + lane * 8);
            const short8 b3 = *(const short8*)(Vl + (2 * 32 + ks) * 512 + lane * 8);
            acc[0][0] = __builtin_amdgcn_mfma_f32_16x16x32_bf16(ha[kk],  bpre0[kk], acc[0][0], 0, 0, 0);
            acc[0][1] = __builtin_amdgcn_mfma_f32_16x16x32_bf16(hbv[kk], bpre0[kk], acc[0][1], 0, 0, 0);
            acc[1][0] = __builtin_amdgcn_mfma_f32_16x16x32_bf16(ha[kk],  b1, acc[1][0], 0, 0, 0);
            acc[1][1] = __builtin_amdgcn_mfma_f32_16x16x32_bf16(hbv[kk], b1, acc[1][1], 0, 0, 0);
            acc[2][0] = __builtin_amdgcn_mfma_f32_16x16x32_bf16(ha[kk],  b2, acc[2][0], 0, 0, 0);
            acc[2][1] = __builtin_amdgcn_mfma_f32_16x16x32_bf16(hbv[kk], b2, acc[2][1], 0, 0, 0);
            acc[3][0] = __builtin_amdgcn_mfma_f32_16x16x32_bf16(ha[kk],  b3, acc[3][0], 0, 0, 0);
            acc[3][1] = __builtin_amdgcn_mfma_f32_16x16x32_bf16(hbv[kk], b3, acc[3][1], 0, 0, 0);
        }

        // ---- 3) part write/read fenced by two syncthreads (off release path) ----
        __syncthreads();   // prev iteration's part reads done before overwrite
#pragma unroll
        for (int g = 0; g < 4; ++g)
#pragma unroll
            for (int mt = 0; mt < 2; ++mt)
#pragma unroll
                for (int r = 0; r < 4; ++r)
                    part[w][g][mt][q * 4 + r][lm] = acc[g][mt][r];
        __syncthreads();

        float z_a[4], z_b[4];
#pragma unroll
        for (int g = 0; g < 4; ++g) {
            z_a[g] = zclamp(bf2f(xva[g]) + part[0][g][0][em][en] + part[1][g][0][em][en]
                                         + part[2][g][0][em][en] + part[3][g][0][em][en]);
            z_b[g] = zclamp(bf2f(xvb[g]) + part[0][g][1][em][en] + part[1][g][1][em][en]
                                         + part[2][g][1][em][en] + part[3][g][1][em][en]);
        }

        float ia = sigm(z_a[0]), fa = sigm(z_a[1]), ga = tanh_(z_a[2]), oa = sigm(z_a[3]);
        c_a = fa * c_a + ia * ga;
        hA = oa * tanh_(c_a);
        float ib = sigm(z_b[0]), fb = sigm(z_b[1]), gb = tanh_(z_b[2]), ob = sigm(z_b[3]);
        c_b = fb * c_b + ib * gb;
        hB = ob * tanh_(c_b);

        hAb = f2bf(hA); hBb = f2bf(hB);

        // ---- 4) h-stores (sc1) -> per-wave drain -> per-wave flag release ----
        u16* hn = h_bf + (par ^ 1) * (B_ * H_);
        __hip_atomic_store(&hn[em * H_ + ncol],        hAb, __ATOMIC_RELAXED, __HIP_MEMORY_SCOPE_AGENT);
        __hip_atomic_store(&hn[(em + 16) * H_ + ncol], hBb, __ATOMIC_RELAXED, __HIP_MEMORY_SCOPE_AGENT);
        asm volatile("s_waitcnt vmcnt(0)" ::: "memory");   // this wave's h-stores acked
        if (lane == 0)
            __hip_atomic_store(&flags[nb * 16 + w], t + 1, __ATOMIC_RELAXED, __HIP_MEMORY_SCOPE_AGENT);

        // ---- 5) post-flag: out-stores for step t + xu(t+1) prefetch ----
        {
            const size_t oA = ((size_t)em * S_ + t) * H_ + ncol;
            const size_t oB = ((size_t)(em + 16) * S_ + t) * H_ + ncol;
            if (isbf) { outh[oA] = hAb; outh[oB] = hBb; }
            else      { outf[oA] = hA;  outf[oB] = hB;  }
        }
        {
            const u16* xt = xu + (size_t)((t + 1) & (S_ - 1)) * (B_ * 4 * H_);
#pragma unroll
            for (int g = 0; g < 4; ++g) {
                xva[g] = xt[em * 4096 + g * 1024 + ncol];
                xvb[g] = xt[(em + 16) * 4096 + g * 1024 + ncol];
            }
        }
    }

    // ---- epilogue: final h/c ----
    {
        const size_t HS = (size_t)B_ * S_ * H_;
        const size_t hA_i = HS + (size_t)em * H_ + ncol;
        const size_t hB_i = HS + (size_t)(em + 16) * H_ + ncol;
        const size_t cA_i = HS + (size_t)B_ * H_ + (size_t)em * H_ + ncol;
        const size_t cB_i = HS + (size_t)B_ * H_ + (size_t)(em + 16) * H_ + ncol;
        if (isbf) {
            outh[hA_i] = hAb; outh[hB_i] = hBb;
            outh[cA_i] = f2bf(c_a); outh[cB_i] = f2bf(c_b);
        } else {
            outf[hA_i] = hA; outf[hB_i] = hB;
            outf[cA_i] = c_a; outf[cB_i] = c_b;
        }
    }
}

// ---------------- host ----------------

extern "C" void kernel_launch(void* const* d_in, const int* in_sizes, int n_in,
                              void* d_out, int out_size, void* d_ws, size_t ws_size,
                              hipStream_t stream) {
    (void)in_sizes; (void)n_in; (void)out_size;
    if (ws_size < WS_NEED) return;   // diagnostic: out stays 0 -> absmax ~0.89 signature
    const void* x  = d_in[0];
    const void* h0 = d_in[1];
    const void* c0 = d_in[2];
    const void* U0 = d_in[3],  *V0 = d_in[4],  *bb0 = d_in[5];
    const void* U1 = d_in[6],  *V1 = d_in[7],  *bb1 = d_in[8];
    const void* U2 = d_in[9],  *V2 = d_in[10], *bb2 = d_in[11];
    const void* U3 = d_in[12], *V3 = d_in[13], *bb3 = d_in[14];

    char* ws = (char*)d_ws;
    int*   flags = (int*)(ws + OFF_FLG);     // 64 WGs x {4 wave flags} @ 64B stride
    int*   dflg  = (int*)(ws + OFF_DFLG);    // dtype flag
    u16*   hbf   = (u16*)(ws + OFF_HBF);
    float* bias  = (float*)(ws + OFF_BIAS);
    u16*   Ut    = (u16*)(ws + OFF_UT);
    u16*   Vp    = (u16*)(ws + OFF_VP);
    u16*   xu    = (u16*)(ws + OFF_XU);

    hipMemsetAsync(flags, 0, 16384, stream);
    prep_probe<<<dim3(1), dim3(64), 0, stream>>>(x, dflg);
    prep_misc<<<dim3(144), dim3(256), 0, stream>>>(bb0, bb1, bb2, bb3, bias, h0, hbf, dflg);
    prep_ut<<<dim3(2048), dim3(256), 0, stream>>>(U0, U1, U2, U3, Ut, dflg);
    prep_vp<<<dim3(2048), dim3(256), 0, stream>>>(V0, V1, V2, V3, Vp, dflg);
    gemm_xu<<<dim3(4096), dim3(256), 0, stream>>>(x, Ut, bias, xu, dflg);
    lstm_rec<<<dim3(NBLK), dim3(256), 0, stream>>>(xu, Vp, c0, hbf, (void*)d_out, flags, dflg);
}